// Round 9
// baseline (381.098 us; speedup 1.0000x reference)
//
#include <hip/hip_runtime.h>
#include <hip/hip_bf16.h>
#include <math.h>

// pool_cross on MI355X — round 16.
// Budget audit (delta-calibrated): conv3 pair 151us, b2 ~8, uv_mfma ~18,
// leaving ~170us invisible in k_prep + k_merge + gaps. Largest identified
// mechanism: k_prep's 67.6KB static LDS caps ALL 1665 blocks at 2/CU ->
// 3.25 serial occupancy rounds paced by ~12us xprep blocks.
//   (1) xprep split-ci: transpose in two 128-ci halves via [128][132] LDS
//       (33.8KB -> 4 blocks/CU, ~1.6 rounds). Same verified swizzle.
//   (2) k_b2 fused into k_uv_mfma: B-tile built on the fly per K-step
//       (regs -> swizzled ds_write_b128, slot = c ^ (rb&7) matching the
//       read side), sourcing cmax/rmax from L2. -1 dispatch, -Bm traffic.
// conv3 / merge byte-identical to the verified r7/r15 forms.
//
// pool algebra (verified): bottom(top(a)) = colmax bcast, right(left(a)) =
// rowmax bcast; merge conv input is rank-1 -> 1-D k_uv decomposition.
// Pool maxes via atomicMax on fp32 bits (valid: values >= 0 post-relu).

constexpr int NB   = 4;
constexpr int CDIM = 256;
constexpr int CMID = 128;
constexpr int HS   = 128;
constexpr int WS   = 128;
constexpr float EPS = 1e-5f;

typedef __bf16 bf16x8 __attribute__((ext_vector_type(8)));
typedef float  f32x4  __attribute__((ext_vector_type(4)));

#define AS1 __attribute__((address_space(1)))
#define AS3 __attribute__((address_space(3)))

__device__ __forceinline__ void load16_lds(const void* gsrc, void* ldst) {
    __builtin_amdgcn_global_load_lds((const AS1 unsigned int*)gsrc,
                                     (AS3 unsigned int*)ldst, 16, 0, 0);
}

// ---------------------------------------------------------------------------
// Fused prep: blocks 0..511 = xprep (x[b][ci][y][x] fp32 -> Xc[b][y][x][ci]
// bf16, LDS transpose in TWO 128-ci halves, 33.8KB LDS -> 4 blocks/CU);
// blocks 512..1664 = weight prep + zero-fill + sA (two 256-thr units each).
__global__ __launch_bounds__(512) void k_prep(
    const float* __restrict__ xin, __hip_bfloat16* __restrict__ Xc,
    const float* __restrict__ p1w, const float* __restrict__ p2w,
    const float* __restrict__ c2w, const float* __restrict__ c1w,
    const float* __restrict__ pw,
    __hip_bfloat16* __restrict__ Aw1, __hip_bfloat16* __restrict__ Aw2,
    __hip_bfloat16* __restrict__ Aw5, __hip_bfloat16* __restrict__ Aw4,
    __hip_bfloat16* __restrict__ sA,
    f32x4* __restrict__ zdst)
{
    __shared__ __hip_bfloat16 lds[128 * 132];   // [x][ci'], one 128-ci half
    const int bid = blockIdx.x;
    const int t   = threadIdx.x;

    if (bid < 512) {
        const int y = bid >> 2;
        const int b = bid & 3;
        const float* xrow = xin + ((size_t)b * CDIM * HS + y) * WS;
#pragma unroll 1
        for (int h = 0; h < 2; ++h) {
            if (h) __syncthreads();          // half-0 reads done before reuse
            const float* xh = xrow + (size_t)h * 128 * HS * WS;
#pragma unroll
            for (int k = 0; k < 4; ++k) {
                int idx = t + k * 512;        // 0..2047
                int cip = idx >> 5;           // local ci pair 0..63
                int x4  = idx & 31;
                int ci  = cip * 2;
                f32x4 va = *(const f32x4*)(xh + (size_t)ci       * HS * WS + x4 * 4);
                f32x4 vb = *(const f32x4*)(xh + (size_t)(ci + 1) * HS * WS + x4 * 4);
                const int cis = ci ^ ((x4 & 7) << 3);   // swizzle bits 3..5
#pragma unroll
                for (int j = 0; j < 4; ++j) {
                    __hip_bfloat162 pv;
                    pv.x = __float2bfloat16(va[j]);
                    pv.y = __float2bfloat16(vb[j]);
                    *(__hip_bfloat162*)(lds + (size_t)(x4 * 4 + j) * 132 + cis) = pv;
                }
            }
            __syncthreads();
#pragma unroll
            for (int k = 0; k < 4; ++k) {
                int i = t + k * 512;          // 0..2047 chunks of 16B
                int x = i >> 4, c8 = i & 15;
                int cb = c8 ^ ((x >> 2) & 7); // inverse swizzle
                bf16x8 vv = *(const bf16x8*)(lds + (size_t)x * 132 + cb * 8);
                *(bf16x8*)(Xc + ((size_t)(b * 128 + y) * 128 + x) * 256
                           + h * 128 + c8 * 8) = vv;
            }
        }
        return;
    }

    // unit u, tl = thread 0..255
    const int u  = (bid - 512) * 2 + (t >> 8);
    const int tl = t & 255;
    if (u < 512) {
        const float* W; __hip_bfloat16* A; int co;
        if (u < 128)      { W = p1w; A = Aw1; co = u; }
        else if (u < 256) { W = p2w; A = Aw2; co = u - 128; }
        else              { W = c2w; A = Aw5; co = u - 256; }
#pragma unroll
        for (int tap = 0; tap < 9; ++tap)
            A[(size_t)co * 2304 + tap * 256 + tl] =
                __float2bfloat16(W[((size_t)co * CDIM + tl) * 9 + tap]);
    } else if (u < 640) {
        int base = (u - 512) * 512 + tl;
        Aw4[base]       = __float2bfloat16(c1w[base]);
        Aw4[base + 256] = __float2bfloat16(c1w[base + 256]);
    } else if (u < 768) {
        zdst[(size_t)(u - 640) * 256 + tl] = (f32x4){0.f, 0.f, 0.f, 0.f};
    } else if (u == 768) {
        if (tl < 16) zdst[32768 + tl] = (f32x4){0.f, 0.f, 0.f, 0.f};
    } else if (u >= 770 && u < 2306) {
        // sA: combined merge-conv weights for the U/V GEMM.
        const int su  = u - 770;           // 0..1535
        const int m   = su >= 768;
        const int rem = su - m * 768;
        const int v   = rem >> 8;          // 0..2
        const int co  = rem & 255;
        const float* w9p = pw + ((size_t)co * CMID) * 9;
#pragma unroll
        for (int rep = 0; rep < 2; ++rep) {
            int kk = tl + rep * 256;
            if (kk < 384) {
                int ci = kk / 3, k = kk - 3 * (kk / 3);
                const float* w9 = w9p + (size_t)ci * 9;
                int i0 = m ? k * 3 + 0 : k;
                int i1 = m ? k * 3 + 1 : 3 + k;
                int i2 = m ? k * 3 + 2 : 6 + k;
                float s = w9[i1];                 // j=1 always
                if (v >= 1) s += w9[i0];          // j=0 for v in {1,2}
                if (v <= 1) s += w9[i2];          // j=2 for v in {0,1}
                sA[((size_t)(m * 3 + v) * 256 + co) * 384 + kk] = __float2bfloat16(s);
            }
        }
    }
}

// ---------------------------------------------------------------------------
// Conv3x3 implicit GEMM v2 (r7 proven, verbatim): 2 y-rows x 128co x 128x
// per block, 32-ci chunks, 64B LDS rows with slot = c ^ ((row>>1)&3)
// swizzle (8-row bank-group period).
// MODE 0: plain fp32 NCHW store (K5, nontemporal). MODE 1: fused branches
// (K1+K2): blockIdx.y==0 -> colmax atomics, ==1 -> rowmax (LDS pre-reduce).
template<int MODE>
__global__ __launch_bounds__(256, 2) void k_conv3(
    const __hip_bfloat16* __restrict__ Xc,
    const __hip_bfloat16* __restrict__ AwA, const __hip_bfloat16* __restrict__ AwB,
    const float* __restrict__ zbuf,
    const float* __restrict__ g1, const float* __restrict__ b1,
    const float* __restrict__ m1, const float* __restrict__ v1,
    const float* __restrict__ g2, const float* __restrict__ b2,
    const float* __restrict__ m2, const float* __restrict__ v2,
    float* __restrict__ out0, unsigned* __restrict__ cmax,
    unsigned* __restrict__ rmax, int CO)
{
    const int y0     = blockIdx.x * 2;
    const int branch = blockIdx.y;              // MODE1: branch; MODE0: co-tile
    const int b      = blockIdx.z;
    const int co0    = (MODE == 0) ? branch * 128 : 0;

    const __hip_bfloat16* Aw = (MODE == 1 && branch) ? AwB : AwA;
    const float* gg  = (MODE == 1 && branch) ? g2 : g1;
    const float* bbp = (MODE == 1 && branch) ? b2 : b1;
    const float* mmp = (MODE == 1 && branch) ? m2 : m1;
    const float* vvp = (MODE == 1 && branch) ? v2 : v1;

    __shared__ __hip_bfloat16 smem[644 * 32];   // 644 rows x 64 B = 41,216 B
    __shared__ float s_sc[128], s_sh[128];
    __shared__ unsigned s_red[2][128];
    char* smb = (char*)smem;

    const int t    = threadIdx.x;
    const int lane = t & 63;
    const int w    = t >> 6;
    const int ml   = lane & 15;
    const int q    = lane >> 4;
    const int mbase = (w >> 1) * 64;
    const int nbase = (w & 1) * 64;

    if (t < 128) {
        int co = co0 + t;
        float iv = rsqrtf(vvp[co] + EPS);
        float sc = gg[co] * iv;
        s_sc[t] = sc;
        s_sh[t] = bbp[co] - mmp[co] * sc;
        if (MODE == 1) { s_red[0][t] = 0u; s_red[1][t] = 0u; }
    }

    f32x4 acc[2][4][4];
#pragma unroll
    for (int yy = 0; yy < 2; ++yy)
#pragma unroll
        for (int mt = 0; mt < 4; ++mt)
#pragma unroll
            for (int nt = 0; nt < 4; ++nt)
                acc[yy][mt][nt] = (f32x4){0.f, 0.f, 0.f, 0.f};

    const __hip_bfloat16* bbase = Xc + (size_t)(b * 128) * 128 * 256;

#pragma unroll 1
    for (int ky = 0; ky < 3; ++ky) {
        const int yd0 = y0 + ky - 1;
        const __hip_bfloat16* arow = Aw + (size_t)co0 * 2304 + (3 * ky) * 256;
#pragma unroll 1
        for (int cih = 0; cih < 8; ++cih) {
            const int cb = cih * 32;
            // stage 2576 x 16B; slot sl holds logical chunk sl^((row>>1)&3)
#pragma unroll
            for (int p = 0; p < 11; ++p) {
                int i = t + p * 256;
                if (i < 2576) {
                    int row = i >> 2, sl = i & 3;
                    int c = sl ^ ((row >> 1) & 3);
                    const __hip_bfloat16* src;
                    if (row < 384) {
                        int j = row >> 7, col = row & 127;
                        src = arow + (size_t)col * 2304 + j * 256 + cb + c * 8;
                    } else {
                        int rbi = row - 384;
                        int yy  = rbi >= 130;
                        int xi  = rbi - 130 * yy;
                        int gy  = yd0 + yy, gx = xi - 1;
                        src = ((unsigned)gy < 128u && (unsigned)gx < 128u)
                            ? bbase + ((size_t)(gy * 128 + gx)) * 256 + cb + c * 8
                            : (const __hip_bfloat16*)((const char*)zbuf + c * 16);
                    }
                    load16_lds(src, smb + (size_t)i * 16);
                }
            }
            __syncthreads();
            // 3 kx, A-frag shared across 2 y rows
#pragma unroll
            for (int j = 0; j < 3; ++j) {
                bf16x8 af[4];
#pragma unroll
                for (int mt = 0; mt < 4; ++mt) {
                    const int ra = j * 128 + mbase + mt * 16 + ml;
                    const int sa = q ^ ((ra >> 1) & 3);
                    af[mt] = *(const bf16x8*)(smb + (size_t)ra * 64 + sa * 16);
                }
#pragma unroll
                for (int yy = 0; yy < 2; ++yy) {
                    bf16x8 bfv[4];
#pragma unroll
                    for (int nt = 0; nt < 4; ++nt) {
                        const int rb = 384 + yy * 130 + nbase + nt * 16 + ml + j;
                        const int sb = q ^ ((rb >> 1) & 3);
                        bfv[nt] = *(const bf16x8*)(smb + (size_t)rb * 64 + sb * 16);
                    }
#pragma unroll
                    for (int mt = 0; mt < 4; ++mt)
#pragma unroll
                        for (int nt = 0; nt < 4; ++nt)
                            acc[yy][mt][nt] = __builtin_amdgcn_mfma_f32_16x16x32_bf16(
                                af[mt], bfv[nt], acc[yy][mt][nt], 0, 0, 0);
                }
            }
            __syncthreads();
        }
    }

    // epilogue. C/D: col(x)=ml, row(co)=q*4+r.
#pragma unroll
    for (int mt = 0; mt < 4; ++mt) {
#pragma unroll
        for (int r = 0; r < 4; ++r) {
            const int col = mbase + mt * 16 + q * 4 + r;
            const float sc = s_sc[col], sh = s_sh[col];
            const int co = co0 + col;
            unsigned rmx0 = 0u, rmx1 = 0u;
#pragma unroll
            for (int nt = 0; nt < 4; ++nt) {
                float va = fmaxf(acc[0][mt][nt][r] * sc + sh, 0.f);
                float vb = fmaxf(acc[1][mt][nt][r] * sc + sh, 0.f);
                const int x = nbase + nt * 16 + ml;
                if (MODE == 0) {
                    __builtin_nontemporal_store(va,
                        out0 + (((size_t)b * CO + co) * HS + y0)     * WS + x);
                    __builtin_nontemporal_store(vb,
                        out0 + (((size_t)b * CO + co) * HS + y0 + 1) * WS + x);
                } else if (branch == 0) {
                    atomicMax(cmax + ((size_t)(b * 128 + co)) * 128 + x,
                              __float_as_uint(fmaxf(va, vb)));
                } else {
                    rmx0 = max(rmx0, __float_as_uint(va));
                    rmx1 = max(rmx1, __float_as_uint(vb));
                }
            }
            if (MODE == 1 && branch == 1) {
                atomicMax(&s_red[0][col], rmx0);
                atomicMax(&s_red[1][col], rmx1);
            }
        }
    }
    if (MODE == 1 && branch == 1) {
        __syncthreads();
        if (t < 128) {
            atomicMax(rmax + ((size_t)(b * 128 + t)) * 128 + y0,     s_red[0][t]);
            atomicMax(rmax + ((size_t)(b * 128 + t)) * 128 + y0 + 1, s_red[1][t]);
        }
    }
}

// ---------------------------------------------------------------------------
// K3: U/V as MFMA GEMM with fused im2col (replaces k_b2 + old k_uv_mfma).
// Per block (v, b, m): Out[256co][128p] over K=384 (ci*3 taps), 6 K-steps.
// A rows staged via global_load_lds from sA; B rows (im2col of cmax/rmax)
// built in registers from L2-hot fp32 and ds_write'd with the SAME slot
// swizzle sl = c ^ (rb&7) the read side expects.
// U written co-major [v][b][co][p]; V written p-major [v][b][p][co].
__global__ __launch_bounds__(256, 2) void k_uv_mfma(
    const __hip_bfloat16* __restrict__ sA, const float* __restrict__ cm,
    const float* __restrict__ rm,
    __hip_bfloat16* __restrict__ U, __hip_bfloat16* __restrict__ V)
{
    const int v = blockIdx.x;   // variant 0..2
    const int b = blockIdx.y;   // batch
    const int m = blockIdx.z;   // mode: 0 -> U, 1 -> V
    const __hip_bfloat16* A = sA + (size_t)((m * 3 + v) * 256) * 384;
    const float* basep = ((m == 0) ? cm : rm) + (size_t)b * 128 * 128;

    __shared__ __hip_bfloat16 smem[24576];   // 48 KB: 384 rows x 128 B
    char* smb = (char*)smem;
    const int t = threadIdx.x, lane = t & 63, w = t >> 6;
    const int ml = lane & 15, q = lane >> 4;
    const int mbase = w * 64;                // wave's co offset

    // B-build constants: thread covers row p = t>>1, K-elements kb..kb+31
    const int bp = t >> 1;
    const int kb = (t & 1) * 32;
    const int rbw = 256 + bp;                // LDS row for B
    const int swz = rbw & 7;

    f32x4 acc[4][8];
#pragma unroll
    for (int mt = 0; mt < 4; ++mt)
#pragma unroll
        for (int nt = 0; nt < 8; ++nt)
            acc[mt][nt] = (f32x4){0.f, 0.f, 0.f, 0.f};

#pragma unroll 1
    for (int ks = 0; ks < 6; ++ks) {
        // A: 256 rows x 8 chunks = 2048 x 16B via global_load_lds
#pragma unroll
        for (int pgl = 0; pgl < 8; ++pgl) {
            int i = t + pgl * 256;           // 0..2047
            int row = i >> 3, sl = i & 7;
            int c   = sl ^ (row & 7);
            load16_lds(A + (size_t)row * 384 + ks * 64 + c * 8,
                       smb + (size_t)i * 16);
        }
        // B: im2col on the fly -> 4 swizzled ds_write_b128 per thread
#pragma unroll
        for (int j = 0; j < 4; ++j) {
            bf16x8 pk;
#pragma unroll
            for (int e = 0; e < 8; ++e) {
                int K   = ks * 64 + kb + j * 8 + e;
                int ci  = K / 3;
                int tap = K - ci * 3;
                int pos = bp + tap - 1;
                float vv = ((unsigned)pos < 128u) ? basep[ci * 128 + pos] : 0.f;
                pk[e] = (__bf16)vv;
            }
            int c  = (kb >> 3) + j;          // logical 16B chunk 0..7
            int sl = c ^ swz;
            *(bf16x8*)(smb + ((size_t)rbw * 8 + sl) * 16) = pk;
        }
        __syncthreads();                     // drains lds-DMA + ds_writes
#pragma unroll
        for (int s = 0; s < 2; ++s) {
            bf16x8 af[4], bfv[8];
#pragma unroll
            for (int mt = 0; mt < 4; ++mt) {
                const int ra = mbase + mt * 16 + ml;
                const int coff = ((s * 4 + q) ^ (ra & 7)) * 16;
                af[mt] = *(const bf16x8*)(smb + (size_t)ra * 128 + coff);
            }
#pragma unroll
            for (int nt = 0; nt < 8; ++nt) {
                const int rb = 256 + nt * 16 + ml;
                const int coff = ((s * 4 + q) ^ (rb & 7)) * 16;
                bfv[nt] = *(const bf16x8*)(smb + (size_t)rb * 128 + coff);
            }
#pragma unroll
            for (int mt = 0; mt < 4; ++mt)
#pragma unroll
                for (int nt = 0; nt < 8; ++nt)
                    acc[mt][nt] = __builtin_amdgcn_mfma_f32_16x16x32_bf16(
                        af[mt], bfv[nt], acc[mt][nt], 0, 0, 0);
        }
        __syncthreads();
    }

    // epilogue: C/D col(p)=ml, row(co)=q*4+r.
    if (m == 0) {
        __hip_bfloat16* dst = U + ((size_t)(v * NB + b) * CDIM) * 128;
#pragma unroll
        for (int mt = 0; mt < 4; ++mt)
#pragma unroll
            for (int nt = 0; nt < 8; ++nt)
#pragma unroll
                for (int r = 0; r < 4; ++r) {
                    const int co = mbase + mt * 16 + q * 4 + r;
                    const int p  = nt * 16 + ml;
                    dst[(size_t)co * 128 + p] = __float2bfloat16(acc[mt][nt][r]);
                }
    } else {
        // V transposed: [v][b][p][co], 4 consecutive co packed per 8B store
        char* dstb = (char*)V + ((size_t)(v * NB + b) * 128) * 256 * 2;
#pragma unroll
        for (int mt = 0; mt < 4; ++mt)
#pragma unroll
            for (int nt = 0; nt < 8; ++nt) {
                const int p = nt * 16 + ml;
                unsigned long long pk = 0;
#pragma unroll
                for (int r = 0; r < 4; ++r) {
                    __hip_bfloat16 hb = __float2bfloat16(acc[mt][nt][r]);
                    unsigned short bits;
                    __builtin_memcpy(&bits, &hb, 2);
                    pk |= (unsigned long long)bits << (16 * r);
                }
                *(unsigned long long*)(dstb +
                    ((size_t)p * 256 + mbase + mt * 16 + q * 4) * 2) = pk;
            }
    }
}

// ---------------------------------------------------------------------------
// K4 v2: merge as MFMA GEMM, 256co x 128x per block (one y row), 4 waves,
// wave = 64co x 128x (acc 4x8). 128B LDS rows, slot = c ^ (row&7) swizzle.
// Rc[b][y][x][co] = relu(psc*(U+V)+psh + csc*conv1x1+csh), bf16.
// V is [v][b][p][co] -> init reads coalesced.
__global__ __launch_bounds__(256, 2) void k_merge_mfma(
    const __hip_bfloat16* __restrict__ Xc, const __hip_bfloat16* __restrict__ Aw4,
    const __hip_bfloat16* __restrict__ U, const __hip_bfloat16* __restrict__ V,
    const float* __restrict__ pg, const float* __restrict__ pb,
    const float* __restrict__ pm, const float* __restrict__ pv,
    const float* __restrict__ cg, const float* __restrict__ cb,
    const float* __restrict__ cmn, const float* __restrict__ cv,
    __hip_bfloat16* __restrict__ Rc)
{
    const int y = blockIdx.x;
    const int b = blockIdx.y;
    __shared__ __hip_bfloat16 smem[32768];   // 64 KB: GEMM staging, then U tiles
    __shared__ float s_psc[256], s_psh[256], s_csc[256], s_csh[256];
    __shared__ float s_v0[256], s_vm[256], s_v1[256];
    char* smb = (char*)smem;
    const int t = threadIdx.x, lane = t & 63, w = t >> 6;
    const int ml = lane & 15, q = lane >> 4;
    const int mbase = w * 64;                // wave's co offset
    const int yc = (y == 0) ? 0 : ((y == HS - 1) ? 2 : 1);

    {   // 256 threads cover 256 co; V reads coalesced
        int co = t;
        float iv = rsqrtf(pv[co] + EPS);
        float psc = pg[co] * iv;
        s_psc[co] = psc;
        s_psh[co] = pb[co] - pm[co] * psc;
        float iv2 = rsqrtf(cv[co] + EPS);
        float csc = cg[co] * iv2;
        s_csc[co] = csc;
        s_csh[co] = cb[co] - cmn[co] * csc;
        const size_t vb2 = ((size_t)b * 128 + y) * 256 + co;
        const size_t cstr2 = (size_t)NB * 128 * 256;
        s_v0[co] = __bfloat162float(V[vb2]);
        s_vm[co] = __bfloat162float(V[cstr2 + vb2]);
        s_v1[co] = __bfloat162float(V[2 * cstr2 + vb2]);
    }

    f32x4 acc[4][8];
#pragma unroll
    for (int mt = 0; mt < 4; ++mt)
#pragma unroll
        for (int nt = 0; nt < 8; ++nt)
            acc[mt][nt] = (f32x4){0.f, 0.f, 0.f, 0.f};

    const __hip_bfloat16* brow = Xc + (size_t)(b * 128 + y) * 128 * 256;
#pragma unroll 1
    for (int ks = 0; ks < 4; ++ks) {
        // stage 384 rows x 128B: A rows 0..255 (co), B rows 256..383 (x)
#pragma unroll
        for (int p = 0; p < 12; ++p) {
            int i   = t + p * 256;           // 0..3071
            int row = i >> 3, sl = i & 7;
            int c   = sl ^ (row & 7);
            const __hip_bfloat16* src = (row < 256)
                ? Aw4 + (size_t)row * 256 + ks * 64 + c * 8
                : brow + (size_t)(row - 256) * 256 + ks * 64 + c * 8;
            load16_lds(src, smb + (size_t)i * 16);
        }
        __syncthreads();
#pragma unroll
        for (int s = 0; s < 2; ++s) {
            bf16x8 af[4], bfv[8];
#pragma unroll
            for (int mt = 0; mt < 4; ++mt) {
                const int ra = mbase + mt * 16 + ml;
                const int coff = ((s * 4 + q) ^ (ra & 7)) * 16;
                af[mt] = *(const bf16x8*)(smb + (size_t)ra * 128 + coff);
            }
#pragma unroll
            for (int nt = 0; nt < 8; ++nt) {
                const int rb = 256 + nt * 16 + ml;
                const int coff = ((s * 4 + q) ^ (rb & 7)) * 16;
                bfv[nt] = *(const bf16x8*)(smb + (size_t)rb * 128 + coff);
            }
#pragma unroll
            for (int mt = 0; mt < 4; ++mt)
#pragma unroll
                for (int nt = 0; nt < 8; ++nt)
                    acc[mt][nt] = __builtin_amdgcn_mfma_f32_16x16x32_bf16(
                        af[mt], bfv[nt], acc[mt][nt], 0, 0, 0);
        }
        __syncthreads();
    }

    // per-wave U stage: 64co x 128x bf16 = 16 KB at wave offset (contiguous)
    const __hip_bfloat16* Ub = U + ((size_t)(yc * NB + b) * CDIM + mbase) * 128;
#pragma unroll
    for (int k = 0; k < 16; ++k) {
        int i = lane + k * 64;
        load16_lds(Ub + (size_t)i * 8, smb + (size_t)w * 16384 + (size_t)i * 16);
    }
    __syncthreads();
    const __hip_bfloat16* ulds = smem + w * 8192;

#pragma unroll
    for (int mt = 0; mt < 4; ++mt) {
#pragma unroll
        for (int nt = 0; nt < 8; ++nt) {
            const int x = nt * 16 + ml;
            unsigned long long pk = 0;
#pragma unroll
            for (int r = 0; r < 4; ++r) {
                const int cl = mt * 16 + q * 4 + r;       // local co in wave
                const int co = mbase + cl;
                float u  = __bfloat162float(ulds[cl * 128 + x]);
                float vt = (x == 0) ? s_v0[co] : ((x == WS - 1) ? s_v1[co] : s_vm[co]);
                float val = fmaxf((u + vt) * s_psc[co] + s_psh[co]
                                  + acc[mt][nt][r] * s_csc[co] + s_csh[co], 0.f);
                __hip_bfloat16 hb = __float2bfloat16(val);
                unsigned short bits;
                __builtin_memcpy(&bits, &hb, 2);
                pk |= (unsigned long long)bits << (16 * r);
            }
            *(unsigned long long*)((char*)Rc +
                ((size_t)((b * 128 + y) * 128 + x) * 256 + mbase + mt * 16 + q * 4) * 2) = pk;
        }
    }
}

// ---------------------------------------------------------------------------
extern "C" void kernel_launch(void* const* d_in, const int* in_sizes, int n_in,
                              void* d_out, int out_size, void* d_ws, size_t ws_size,
                              hipStream_t stream)
{
    (void)in_sizes; (void)n_in; (void)out_size; (void)ws_size;
    const float* x    = (const float*)d_in[0];
    const float* p1_w = (const float*)d_in[1];
    const float* p1_g = (const float*)d_in[2];
    const float* p1_b = (const float*)d_in[3];
    const float* p1_m = (const float*)d_in[4];
    const float* p1_v = (const float*)d_in[5];
    const float* p2_w = (const float*)d_in[6];
    const float* p2_g = (const float*)d_in[7];
    const float* p2_b = (const float*)d_in[8];
    const float* p2_m = (const float*)d_in[9];
    const float* p2_v = (const float*)d_in[10];
    const float* p_w  = (const float*)d_in[11];
    const float* p_g  = (const float*)d_in[12];
    const float* p_b  = (const float*)d_in[13];
    const float* p_m  = (const float*)d_in[14];
    const float* p_v  = (const float*)d_in[15];
    const float* c1_w = (const float*)d_in[16];
    const float* c1_g = (const float*)d_in[17];
    const float* c1_b = (const float*)d_in[18];
    const float* c1_m = (const float*)d_in[19];
    const float* c1_v = (const float*)d_in[20];
    const float* c2_w = (const float*)d_in[21];
    const float* c2_g = (const float*)d_in[22];
    const float* c2_b = (const float*)d_in[23];
    const float* c2_m = (const float*)d_in[24];
    const float* c2_v = (const float*)d_in[25];
    float* out = (float*)d_out;
    char* ws = (char*)d_ws;

    // layout (bytes), total 70,516,992 (<= proven-safe 70,778,880):
    //   Xc @0 (33,554,432) | Rc @33,554,432 (33,554,432)
    //     sA @33,554,432 (1,179,648) aliases the head of Rc: dead before
    //     k_merge_mfma writes Rc (stream order).
    //   U @67,108,864 / V @67,895,296 (alias Aw1 @67,108,864, Aw2 @67,698,688)
    //   Aw5 @68,681,728 | Aw4 @69,861,376
    //   zero region @69,992,448 (524,544): cmaxU | rmaxU @70,254,592 | zbuf @70,516,736
    __hip_bfloat16* Xc   = (__hip_bfloat16*)ws;
    __hip_bfloat16* Rc   = (__hip_bfloat16*)(ws + 33554432);
    __hip_bfloat16* sA   = (__hip_bfloat16*)(ws + 33554432);
    __hip_bfloat16* Ubuf = (__hip_bfloat16*)(ws + 67108864);
    __hip_bfloat16* Vbuf = (__hip_bfloat16*)(ws + 67895296);
    __hip_bfloat16* Aw1  = (__hip_bfloat16*)(ws + 67108864);
    __hip_bfloat16* Aw2  = (__hip_bfloat16*)(ws + 67698688);
    __hip_bfloat16* Aw5  = (__hip_bfloat16*)(ws + 68681728);
    __hip_bfloat16* Aw4  = (__hip_bfloat16*)(ws + 69861376);
    unsigned*       cmaxU = (unsigned*)(ws + 69992448);
    unsigned*       rmaxU = (unsigned*)(ws + 70254592);
    float*          zbuf  = (float*)(ws + 70516736);

    // fused prep: xprep (0..511, 33.8KB LDS) + weight prep/zero/sA (512..1664)
    k_prep<<<dim3(1665), 512, 0, stream>>>(
        x, Xc, p1_w, p2_w, c2_w, c1_w, p_w, Aw1, Aw2, Aw5, Aw4, sA,
        (f32x4*)(ws + 69992448));

    // fused K1+K2: blockIdx.y = branch (0: colmax/Aw1, 1: rowmax/Aw2)
    k_conv3<1><<<dim3(64, 2, 4), 256, 0, stream>>>(
        Xc, Aw1, Aw2, zbuf,
        p1_g, p1_b, p1_m, p1_v, p2_g, p2_b, p2_m, p2_v,
        nullptr, cmaxU, rmaxU, CMID);

    // U/V via MFMA GEMM with fused im2col (replaces k_b2 + k_uv_mfma)
    k_uv_mfma<<<dim3(3, 4, 2), 256, 0, stream>>>(
        sA, (const float*)cmaxU, (const float*)rmaxU, Ubuf, Vbuf);

    k_merge_mfma<<<dim3(128, 4), 256, 0, stream>>>(
        Xc, Aw4, Ubuf, Vbuf, p_g, p_b, p_m, p_v,
        c1_g, c1_b, c1_m, c1_v, Rc);

    // K5: blockIdx.y = co-tile
    k_conv3<0><<<dim3(64, 2, 4), 256, 0, stream>>>(
        Rc, Aw5, nullptr, zbuf,
        c2_g, c2_b, c2_m, c2_v, nullptr, nullptr, nullptr, nullptr,
        out, nullptr, nullptr, CDIM);
}

// Round 10
// 349.014 us; speedup vs baseline: 1.0919x; 1.0919x over previous
//
#include <hip/hip_runtime.h>
#include <hip/hip_bf16.h>
#include <math.h>

// pool_cross on MI355X — round 17 (controlled revert to the r15 build).
// r16 delta decomposition: total +31us == conv3 +32us on BYTE-IDENTICAL
// conv3 source (same VGPR/FETCH/conflicts) -> codegen-context perturbation
// (co-compiled kernels share regalloc/sched context) or chip state; and
// r16's prep-occupancy + b2-fusion "wins" netted ~-1us (theory falsified).
// This build is exactly the verified 349.8us source: conv3 r7-verbatim,
// split k_b2 + k_uv_mfma, r15 xprep (pair-load + XOR swizzle), V
// transposed [v][b][p][co] for coalesced merge init.
//
// pool algebra (verified): bottom(top(a)) = colmax bcast, right(left(a)) =
// rowmax bcast; merge conv input is rank-1 -> 1-D k_uv decomposition.
// Pool maxes via atomicMax on fp32 bits (valid: values >= 0 post-relu).

constexpr int NB   = 4;
constexpr int CDIM = 256;
constexpr int CMID = 128;
constexpr int HS   = 128;
constexpr int WS   = 128;
constexpr float EPS = 1e-5f;

typedef __bf16 bf16x8 __attribute__((ext_vector_type(8)));
typedef float  f32x4  __attribute__((ext_vector_type(4)));

#define AS1 __attribute__((address_space(1)))
#define AS3 __attribute__((address_space(3)))

__device__ __forceinline__ void load16_lds(const void* gsrc, void* ldst) {
    __builtin_amdgcn_global_load_lds((const AS1 unsigned int*)gsrc,
                                     (AS3 unsigned int*)ldst, 16, 0, 0);
}

// ---------------------------------------------------------------------------
// Fused prep: blocks 0..511 = xprep (x[b][ci][y][x] fp32 -> Xc[b][y][x][ci]
// bf16, LDS transpose, XOR-swizzled); blocks 512..1664 = weight prep +
// zero-fill + sA (two 256-thread units per block).
__global__ __launch_bounds__(512) void k_prep(
    const float* __restrict__ xin, __hip_bfloat16* __restrict__ Xc,
    const float* __restrict__ p1w, const float* __restrict__ p2w,
    const float* __restrict__ c2w, const float* __restrict__ c1w,
    const float* __restrict__ pw,
    __hip_bfloat16* __restrict__ Aw1, __hip_bfloat16* __restrict__ Aw2,
    __hip_bfloat16* __restrict__ Aw5, __hip_bfloat16* __restrict__ Aw4,
    __hip_bfloat16* __restrict__ sA,
    f32x4* __restrict__ zdst)
{
    __shared__ __hip_bfloat16 lds[128 * 264];   // [x][ci'], ci XOR-swizzled
    const int bid = blockIdx.x;
    const int t   = threadIdx.x;

    if (bid < 512) {
        const int y = bid >> 2;
        const int b = bid & 3;
        const float* xrow = xin + ((size_t)b * CDIM * HS + y) * WS;
#pragma unroll
        for (int k = 0; k < 8; ++k) {
            int idx = t + k * 512;            // 0..4095
            int cip = idx >> 5;               // ci pair 0..127
            int x4  = idx & 31;
            int ci  = cip * 2;
            f32x4 va = *(const f32x4*)(xrow + (size_t)ci       * HS * WS + x4 * 4);
            f32x4 vb = *(const f32x4*)(xrow + (size_t)(ci + 1) * HS * WS + x4 * 4);
            const int cis = ci ^ ((x4 & 7) << 3);   // swizzle: (x>>2)&7 on bits 3..5
#pragma unroll
            for (int j = 0; j < 4; ++j) {
                __hip_bfloat162 pv;
                pv.x = __float2bfloat16(va[j]);
                pv.y = __float2bfloat16(vb[j]);
                *(__hip_bfloat162*)(lds + (size_t)(x4 * 4 + j) * 264 + cis) = pv;
            }
        }
        __syncthreads();
#pragma unroll
        for (int k = 0; k < 8; ++k) {
            int i = t + k * 512;              // 0..4095 chunks of 16B
            int x = i >> 5, c8 = i & 31;
            int cb = c8 ^ ((x >> 2) & 7);     // inverse of the write swizzle
            bf16x8 vv = *(const bf16x8*)(lds + (size_t)x * 264 + cb * 8);
            *(bf16x8*)(Xc + ((size_t)(b * 128 + y) * 128 + x) * 256 + c8 * 8) = vv;
        }
        return;
    }

    // unit u, tl = thread 0..255
    const int u  = (bid - 512) * 2 + (t >> 8);
    const int tl = t & 255;
    if (u < 512) {
        const float* W; __hip_bfloat16* A; int co;
        if (u < 128)      { W = p1w; A = Aw1; co = u; }
        else if (u < 256) { W = p2w; A = Aw2; co = u - 128; }
        else              { W = c2w; A = Aw5; co = u - 256; }
#pragma unroll
        for (int tap = 0; tap < 9; ++tap)
            A[(size_t)co * 2304 + tap * 256 + tl] =
                __float2bfloat16(W[((size_t)co * CDIM + tl) * 9 + tap]);
    } else if (u < 640) {
        int base = (u - 512) * 512 + tl;
        Aw4[base]       = __float2bfloat16(c1w[base]);
        Aw4[base + 256] = __float2bfloat16(c1w[base + 256]);
    } else if (u < 768) {
        zdst[(size_t)(u - 640) * 256 + tl] = (f32x4){0.f, 0.f, 0.f, 0.f};
    } else if (u == 768) {
        if (tl < 16) zdst[32768 + tl] = (f32x4){0.f, 0.f, 0.f, 0.f};
    } else if (u >= 770 && u < 2306) {
        // sA: combined merge-conv weights for the U/V GEMM.
        const int su  = u - 770;           // 0..1535
        const int m   = su >= 768;
        const int rem = su - m * 768;
        const int v   = rem >> 8;          // 0..2
        const int co  = rem & 255;
        const float* w9p = pw + ((size_t)co * CMID) * 9;
#pragma unroll
        for (int rep = 0; rep < 2; ++rep) {
            int kk = tl + rep * 256;
            if (kk < 384) {
                int ci = kk / 3, k = kk - 3 * (kk / 3);
                const float* w9 = w9p + (size_t)ci * 9;
                int i0 = m ? k * 3 + 0 : k;
                int i1 = m ? k * 3 + 1 : 3 + k;
                int i2 = m ? k * 3 + 2 : 6 + k;
                float s = w9[i1];                 // j=1 always
                if (v >= 1) s += w9[i0];          // j=0 for v in {1,2}
                if (v <= 1) s += w9[i2];          // j=2 for v in {0,1}
                sA[((size_t)(m * 3 + v) * 256 + co) * 384 + kk] = __float2bfloat16(s);
            }
        }
    }
}

// ---------------------------------------------------------------------------
// Conv3x3 implicit GEMM v2 (r7 proven, verbatim): 2 y-rows x 128co x 128x
// per block, 32-ci chunks, 64B LDS rows with slot = c ^ ((row>>1)&3)
// swizzle (8-row bank-group period).
// MODE 0: plain fp32 NCHW store (K5, nontemporal). MODE 1: fused branches
// (K1+K2): blockIdx.y==0 -> colmax atomics, ==1 -> rowmax (LDS pre-reduce).
template<int MODE>
__global__ __launch_bounds__(256, 2) void k_conv3(
    const __hip_bfloat16* __restrict__ Xc,
    const __hip_bfloat16* __restrict__ AwA, const __hip_bfloat16* __restrict__ AwB,
    const float* __restrict__ zbuf,
    const float* __restrict__ g1, const float* __restrict__ b1,
    const float* __restrict__ m1, const float* __restrict__ v1,
    const float* __restrict__ g2, const float* __restrict__ b2,
    const float* __restrict__ m2, const float* __restrict__ v2,
    float* __restrict__ out0, unsigned* __restrict__ cmax,
    unsigned* __restrict__ rmax, int CO)
{
    const int y0     = blockIdx.x * 2;
    const int branch = blockIdx.y;              // MODE1: branch; MODE0: co-tile
    const int b      = blockIdx.z;
    const int co0    = (MODE == 0) ? branch * 128 : 0;

    const __hip_bfloat16* Aw = (MODE == 1 && branch) ? AwB : AwA;
    const float* gg  = (MODE == 1 && branch) ? g2 : g1;
    const float* bbp = (MODE == 1 && branch) ? b2 : b1;
    const float* mmp = (MODE == 1 && branch) ? m2 : m1;
    const float* vvp = (MODE == 1 && branch) ? v2 : v1;

    __shared__ __hip_bfloat16 smem[644 * 32];   // 644 rows x 64 B = 41,216 B
    __shared__ float s_sc[128], s_sh[128];
    __shared__ unsigned s_red[2][128];
    char* smb = (char*)smem;

    const int t    = threadIdx.x;
    const int lane = t & 63;
    const int w    = t >> 6;
    const int ml   = lane & 15;
    const int q    = lane >> 4;
    const int mbase = (w >> 1) * 64;
    const int nbase = (w & 1) * 64;

    if (t < 128) {
        int co = co0 + t;
        float iv = rsqrtf(vvp[co] + EPS);
        float sc = gg[co] * iv;
        s_sc[t] = sc;
        s_sh[t] = bbp[co] - mmp[co] * sc;
        if (MODE == 1) { s_red[0][t] = 0u; s_red[1][t] = 0u; }
    }

    f32x4 acc[2][4][4];
#pragma unroll
    for (int yy = 0; yy < 2; ++yy)
#pragma unroll
        for (int mt = 0; mt < 4; ++mt)
#pragma unroll
            for (int nt = 0; nt < 4; ++nt)
                acc[yy][mt][nt] = (f32x4){0.f, 0.f, 0.f, 0.f};

    const __hip_bfloat16* bbase = Xc + (size_t)(b * 128) * 128 * 256;

#pragma unroll 1
    for (int ky = 0; ky < 3; ++ky) {
        const int yd0 = y0 + ky - 1;
        const __hip_bfloat16* arow = Aw + (size_t)co0 * 2304 + (3 * ky) * 256;
#pragma unroll 1
        for (int cih = 0; cih < 8; ++cih) {
            const int cb = cih * 32;
            // stage 2576 x 16B; slot sl holds logical chunk sl^((row>>1)&3)
#pragma unroll
            for (int p = 0; p < 11; ++p) {
                int i = t + p * 256;
                if (i < 2576) {
                    int row = i >> 2, sl = i & 3;
                    int c = sl ^ ((row >> 1) & 3);
                    const __hip_bfloat16* src;
                    if (row < 384) {
                        int j = row >> 7, col = row & 127;
                        src = arow + (size_t)col * 2304 + j * 256 + cb + c * 8;
                    } else {
                        int rbi = row - 384;
                        int yy  = rbi >= 130;
                        int xi  = rbi - 130 * yy;
                        int gy  = yd0 + yy, gx = xi - 1;
                        src = ((unsigned)gy < 128u && (unsigned)gx < 128u)
                            ? bbase + ((size_t)(gy * 128 + gx)) * 256 + cb + c * 8
                            : (const __hip_bfloat16*)((const char*)zbuf + c * 16);
                    }
                    load16_lds(src, smb + (size_t)i * 16);
                }
            }
            __syncthreads();
            // 3 kx, A-frag shared across 2 y rows
#pragma unroll
            for (int j = 0; j < 3; ++j) {
                bf16x8 af[4];
#pragma unroll
                for (int mt = 0; mt < 4; ++mt) {
                    const int ra = j * 128 + mbase + mt * 16 + ml;
                    const int sa = q ^ ((ra >> 1) & 3);
                    af[mt] = *(const bf16x8*)(smb + (size_t)ra * 64 + sa * 16);
                }
#pragma unroll
                for (int yy = 0; yy < 2; ++yy) {
                    bf16x8 bfv[4];
#pragma unroll
                    for (int nt = 0; nt < 4; ++nt) {
                        const int rb = 384 + yy * 130 + nbase + nt * 16 + ml + j;
                        const int sb = q ^ ((rb >> 1) & 3);
                        bfv[nt] = *(const bf16x8*)(smb + (size_t)rb * 64 + sb * 16);
                    }
#pragma unroll
                    for (int mt = 0; mt < 4; ++mt)
#pragma unroll
                        for (int nt = 0; nt < 4; ++nt)
                            acc[yy][mt][nt] = __builtin_amdgcn_mfma_f32_16x16x32_bf16(
                                af[mt], bfv[nt], acc[yy][mt][nt], 0, 0, 0);
                }
            }
            __syncthreads();
        }
    }

    // epilogue. C/D: col(x)=ml, row(co)=q*4+r.
#pragma unroll
    for (int mt = 0; mt < 4; ++mt) {
#pragma unroll
        for (int r = 0; r < 4; ++r) {
            const int col = mbase + mt * 16 + q * 4 + r;
            const float sc = s_sc[col], sh = s_sh[col];
            const int co = co0 + col;
            unsigned rmx0 = 0u, rmx1 = 0u;
#pragma unroll
            for (int nt = 0; nt < 4; ++nt) {
                float va = fmaxf(acc[0][mt][nt][r] * sc + sh, 0.f);
                float vb = fmaxf(acc[1][mt][nt][r] * sc + sh, 0.f);
                const int x = nbase + nt * 16 + ml;
                if (MODE == 0) {
                    __builtin_nontemporal_store(va,
                        out0 + (((size_t)b * CO + co) * HS + y0)     * WS + x);
                    __builtin_nontemporal_store(vb,
                        out0 + (((size_t)b * CO + co) * HS + y0 + 1) * WS + x);
                } else if (branch == 0) {
                    atomicMax(cmax + ((size_t)(b * 128 + co)) * 128 + x,
                              __float_as_uint(fmaxf(va, vb)));
                } else {
                    rmx0 = max(rmx0, __float_as_uint(va));
                    rmx1 = max(rmx1, __float_as_uint(vb));
                }
            }
            if (MODE == 1 && branch == 1) {
                atomicMax(&s_red[0][col], rmx0);
                atomicMax(&s_red[1][col], rmx1);
            }
        }
    }
    if (MODE == 1 && branch == 1) {
        __syncthreads();
        if (t < 128) {
            atomicMax(rmax + ((size_t)(b * 128 + t)) * 128 + y0,     s_red[0][t]);
            atomicMax(rmax + ((size_t)(b * 128 + t)) * 128 + y0 + 1, s_red[1][t]);
        }
    }
}

// ---------------------------------------------------------------------------
// K3a: im2col of cmax/rmax -> Bm[m][b][p][ci*3+k] bf16 (0-padded taps).
__global__ __launch_bounds__(256) void k_b2(
    const float* __restrict__ cm, const float* __restrict__ rm,
    __hip_bfloat16* __restrict__ Bm)
{
    const int p0 = blockIdx.x * 16;
    const int m  = blockIdx.y;
    const int b  = blockIdx.z;
    const int tl = threadIdx.x;
    const float* basep = (m == 0) ? cm : rm;
#pragma unroll
    for (int rep = 0; rep < 2; ++rep) {
        int kk = tl + rep * 256;
        if (kk < 384) {
            int ci = kk / 3, k = kk - 3 * (kk / 3);
            const float* src = basep + ((size_t)b * 128 + ci) * 128;
            __hip_bfloat16* dst = Bm + ((size_t)(m * 4 + b) * 128) * 384 + kk;
#pragma unroll
            for (int pp = 0; pp < 16; ++pp) {
                int p = p0 + pp;
                int pos = p + k - 1;
                float vv = ((unsigned)pos < 128u) ? src[pos] : 0.f;
                dst[(size_t)p * 384] = __float2bfloat16(vv);
            }
        }
    }
}

// ---------------------------------------------------------------------------
// K3b: U/V as MFMA GEMM. Per block (v, b, m): Out[256co][128p] over K=384,
// merge_mfma staging/swizzle/frag structure (proven).
// U written co-major [v][b][co][p] (merge stages rows of x); V written
// p-major [v][b][p][co] with packed 8B stores (merge reads co-runs per y).
__global__ __launch_bounds__(256, 2) void k_uv_mfma(
    const __hip_bfloat16* __restrict__ sA, const __hip_bfloat16* __restrict__ Bm,
    __hip_bfloat16* __restrict__ U, __hip_bfloat16* __restrict__ V)
{
    const int v = blockIdx.x;   // variant 0..2
    const int b = blockIdx.y;   // batch
    const int m = blockIdx.z;   // mode: 0 -> U, 1 -> V
    const __hip_bfloat16* A  = sA + (size_t)((m * 3 + v) * 256) * 384;
    const __hip_bfloat16* Bp = Bm + (size_t)((m * 4 + b) * 128) * 384;

    __shared__ __hip_bfloat16 smem[24576];   // 48 KB: 384 rows x 128 B
    char* smb = (char*)smem;
    const int t = threadIdx.x, lane = t & 63, w = t >> 6;
    const int ml = lane & 15, q = lane >> 4;
    const int mbase = w * 64;                // wave's co offset

    f32x4 acc[4][8];
#pragma unroll
    for (int mt = 0; mt < 4; ++mt)
#pragma unroll
        for (int nt = 0; nt < 8; ++nt)
            acc[mt][nt] = (f32x4){0.f, 0.f, 0.f, 0.f};

#pragma unroll 1
    for (int ks = 0; ks < 6; ++ks) {
        // stage 384 rows x 128B: A rows 0..255 (co), B rows 256..383 (p)
#pragma unroll
        for (int p = 0; p < 12; ++p) {
            int i   = t + p * 256;           // 0..3071
            int row = i >> 3, sl = i & 7;
            int c   = sl ^ (row & 7);
            const __hip_bfloat16* src = (row < 256)
                ? A  + (size_t)row * 384 + ks * 64 + c * 8
                : Bp + (size_t)(row - 256) * 384 + ks * 64 + c * 8;
            load16_lds(src, smb + (size_t)i * 16);
        }
        __syncthreads();
#pragma unroll
        for (int s = 0; s < 2; ++s) {
            bf16x8 af[4], bfv[8];
#pragma unroll
            for (int mt = 0; mt < 4; ++mt) {
                const int ra = mbase + mt * 16 + ml;
                const int coff = ((s * 4 + q) ^ (ra & 7)) * 16;
                af[mt] = *(const bf16x8*)(smb + (size_t)ra * 128 + coff);
            }
#pragma unroll
            for (int nt = 0; nt < 8; ++nt) {
                const int rb = 256 + nt * 16 + ml;
                const int coff = ((s * 4 + q) ^ (rb & 7)) * 16;
                bfv[nt] = *(const bf16x8*)(smb + (size_t)rb * 128 + coff);
            }
#pragma unroll
            for (int mt = 0; mt < 4; ++mt)
#pragma unroll
                for (int nt = 0; nt < 8; ++nt)
                    acc[mt][nt] = __builtin_amdgcn_mfma_f32_16x16x32_bf16(
                        af[mt], bfv[nt], acc[mt][nt], 0, 0, 0);
        }
        __syncthreads();
    }

    // epilogue: C/D col(p)=ml, row(co)=q*4+r.
    if (m == 0) {
        __hip_bfloat16* dst = U + ((size_t)(v * NB + b) * CDIM) * 128;
#pragma unroll
        for (int mt = 0; mt < 4; ++mt)
#pragma unroll
            for (int nt = 0; nt < 8; ++nt)
#pragma unroll
                for (int r = 0; r < 4; ++r) {
                    const int co = mbase + mt * 16 + q * 4 + r;
                    const int p  = nt * 16 + ml;
                    dst[(size_t)co * 128 + p] = __float2bfloat16(acc[mt][nt][r]);
                }
    } else {
        // V transposed: [v][b][p][co], 4 consecutive co packed per 8B store
        char* dstb = (char*)V + ((size_t)(v * NB + b) * 128) * 256 * 2;
#pragma unroll
        for (int mt = 0; mt < 4; ++mt)
#pragma unroll
            for (int nt = 0; nt < 8; ++nt) {
                const int p = nt * 16 + ml;
                unsigned long long pk = 0;
#pragma unroll
                for (int r = 0; r < 4; ++r) {
                    __hip_bfloat16 hb = __float2bfloat16(acc[mt][nt][r]);
                    unsigned short bits;
                    __builtin_memcpy(&bits, &hb, 2);
                    pk |= (unsigned long long)bits << (16 * r);
                }
                *(unsigned long long*)(dstb +
                    ((size_t)p * 256 + mbase + mt * 16 + q * 4) * 2) = pk;
            }
    }
}

// ---------------------------------------------------------------------------
// K4 v2: merge as MFMA GEMM, 256co x 128x per block (one y row), 4 waves,
// wave = 64co x 128x (acc 4x8). 128B LDS rows, slot = c ^ (row&7) swizzle.
// Rc[b][y][x][co] = relu(psc*(U+V)+psh + csc*conv1x1+csh), bf16.
// V is [v][b][p][co] -> init reads coalesced.
__global__ __launch_bounds__(256, 2) void k_merge_mfma(
    const __hip_bfloat16* __restrict__ Xc, const __hip_bfloat16* __restrict__ Aw4,
    const __hip_bfloat16* __restrict__ U, const __hip_bfloat16* __restrict__ V,
    const float* __restrict__ pg, const float* __restrict__ pb,
    const float* __restrict__ pm, const float* __restrict__ pv,
    const float* __restrict__ cg, const float* __restrict__ cb,
    const float* __restrict__ cmn, const float* __restrict__ cv,
    __hip_bfloat16* __restrict__ Rc)
{
    const int y = blockIdx.x;
    const int b = blockIdx.y;
    __shared__ __hip_bfloat16 smem[32768];   // 64 KB: GEMM staging, then U tiles
    __shared__ float s_psc[256], s_psh[256], s_csc[256], s_csh[256];
    __shared__ float s_v0[256], s_vm[256], s_v1[256];
    char* smb = (char*)smem;
    const int t = threadIdx.x, lane = t & 63, w = t >> 6;
    const int ml = lane & 15, q = lane >> 4;
    const int mbase = w * 64;                // wave's co offset
    const int yc = (y == 0) ? 0 : ((y == HS - 1) ? 2 : 1);

    {   // 256 threads cover 256 co; V reads coalesced
        int co = t;
        float iv = rsqrtf(pv[co] + EPS);
        float psc = pg[co] * iv;
        s_psc[co] = psc;
        s_psh[co] = pb[co] - pm[co] * psc;
        float iv2 = rsqrtf(cv[co] + EPS);
        float csc = cg[co] * iv2;
        s_csc[co] = csc;
        s_csh[co] = cb[co] - cmn[co] * csc;
        const size_t vb2 = ((size_t)b * 128 + y) * 256 + co;
        const size_t cstr2 = (size_t)NB * 128 * 256;
        s_v0[co] = __bfloat162float(V[vb2]);
        s_vm[co] = __bfloat162float(V[cstr2 + vb2]);
        s_v1[co] = __bfloat162float(V[2 * cstr2 + vb2]);
    }

    f32x4 acc[4][8];
#pragma unroll
    for (int mt = 0; mt < 4; ++mt)
#pragma unroll
        for (int nt = 0; nt < 8; ++nt)
            acc[mt][nt] = (f32x4){0.f, 0.f, 0.f, 0.f};

    const __hip_bfloat16* brow = Xc + (size_t)(b * 128 + y) * 128 * 256;
#pragma unroll 1
    for (int ks = 0; ks < 4; ++ks) {
        // stage 384 rows x 128B: A rows 0..255 (co), B rows 256..383 (x)
#pragma unroll
        for (int p = 0; p < 12; ++p) {
            int i   = t + p * 256;           // 0..3071
            int row = i >> 3, sl = i & 7;
            int c   = sl ^ (row & 7);
            const __hip_bfloat16* src = (row < 256)
                ? Aw4 + (size_t)row * 256 + ks * 64 + c * 8
                : brow + (size_t)(row - 256) * 256 + ks * 64 + c * 8;
            load16_lds(src, smb + (size_t)i * 16);
        }
        __syncthreads();
#pragma unroll
        for (int s = 0; s < 2; ++s) {
            bf16x8 af[4], bfv[8];
#pragma unroll
            for (int mt = 0; mt < 4; ++mt) {
                const int ra = mbase + mt * 16 + ml;
                const int coff = ((s * 4 + q) ^ (ra & 7)) * 16;
                af[mt] = *(const bf16x8*)(smb + (size_t)ra * 128 + coff);
            }
#pragma unroll
            for (int nt = 0; nt < 8; ++nt) {
                const int rb = 256 + nt * 16 + ml;
                const int coff = ((s * 4 + q) ^ (rb & 7)) * 16;
                bfv[nt] = *(const bf16x8*)(smb + (size_t)rb * 128 + coff);
            }
#pragma unroll
            for (int mt = 0; mt < 4; ++mt)
#pragma unroll
                for (int nt = 0; nt < 8; ++nt)
                    acc[mt][nt] = __builtin_amdgcn_mfma_f32_16x16x32_bf16(
                        af[mt], bfv[nt], acc[mt][nt], 0, 0, 0);
        }
        __syncthreads();
    }

    // per-wave U stage: 64co x 128x bf16 = 16 KB at wave offset (contiguous)
    const __hip_bfloat16* Ub = U + ((size_t)(yc * NB + b) * CDIM + mbase) * 128;
#pragma unroll
    for (int k = 0; k < 16; ++k) {
        int i = lane + k * 64;
        load16_lds(Ub + (size_t)i * 8, smb + (size_t)w * 16384 + (size_t)i * 16);
    }
    __syncthreads();
    const __hip_bfloat16* ulds = smem + w * 8192;

#pragma unroll
    for (int mt = 0; mt < 4; ++mt) {
#pragma unroll
        for (int nt = 0; nt < 8; ++nt) {
            const int x = nt * 16 + ml;
            unsigned long long pk = 0;
#pragma unroll
            for (int r = 0; r < 4; ++r) {
                const int cl = mt * 16 + q * 4 + r;       // local co in wave
                const int co = mbase + cl;
                float u  = __bfloat162float(ulds[cl * 128 + x]);
                float vt = (x == 0) ? s_v0[co] : ((x == WS - 1) ? s_v1[co] : s_vm[co]);
                float val = fmaxf((u + vt) * s_psc[co] + s_psh[co]
                                  + acc[mt][nt][r] * s_csc[co] + s_csh[co], 0.f);
                __hip_bfloat16 hb = __float2bfloat16(val);
                unsigned short bits;
                __builtin_memcpy(&bits, &hb, 2);
                pk |= (unsigned long long)bits << (16 * r);
            }
            *(unsigned long long*)((char*)Rc +
                ((size_t)((b * 128 + y) * 128 + x) * 256 + mbase + mt * 16 + q * 4) * 2) = pk;
        }
    }
}

// ---------------------------------------------------------------------------
extern "C" void kernel_launch(void* const* d_in, const int* in_sizes, int n_in,
                              void* d_out, int out_size, void* d_ws, size_t ws_size,
                              hipStream_t stream)
{
    (void)in_sizes; (void)n_in; (void)out_size; (void)ws_size;
    const float* x    = (const float*)d_in[0];
    const float* p1_w = (const float*)d_in[1];
    const float* p1_g = (const float*)d_in[2];
    const float* p1_b = (const float*)d_in[3];
    const float* p1_m = (const float*)d_in[4];
    const float* p1_v = (const float*)d_in[5];
    const float* p2_w = (const float*)d_in[6];
    const float* p2_g = (const float*)d_in[7];
    const float* p2_b = (const float*)d_in[8];
    const float* p2_m = (const float*)d_in[9];
    const float* p2_v = (const float*)d_in[10];
    const float* p_w  = (const float*)d_in[11];
    const float* p_g  = (const float*)d_in[12];
    const float* p_b  = (const float*)d_in[13];
    const float* p_m  = (const float*)d_in[14];
    const float* p_v  = (const float*)d_in[15];
    const float* c1_w = (const float*)d_in[16];
    const float* c1_g = (const float*)d_in[17];
    const float* c1_b = (const float*)d_in[18];
    const float* c1_m = (const float*)d_in[19];
    const float* c1_v = (const float*)d_in[20];
    const float* c2_w = (const float*)d_in[21];
    const float* c2_g = (const float*)d_in[22];
    const float* c2_b = (const float*)d_in[23];
    const float* c2_m = (const float*)d_in[24];
    const float* c2_v = (const float*)d_in[25];
    float* out = (float*)d_out;
    char* ws = (char*)d_ws;

    // layout (bytes), total 70,516,992 (<= proven-safe 70,778,880):
    //   Xc @0 (33,554,432) | Rc @33,554,432 (33,554,432)
    //     sA @33,554,432 (1,179,648) and Bm @34,734,080 (786,432) alias the
    //     head of Rc: both dead before k_merge_mfma writes Rc (stream order).
    //   U @67,108,864 / V @67,895,296 (alias Aw1 @67,108,864, Aw2 @67,698,688)
    //   Aw5 @68,681,728 | Aw4 @69,861,376
    //   zero region @69,992,448 (524,544): cmaxU | rmaxU @70,254,592 | zbuf @70,516,736
    __hip_bfloat16* Xc   = (__hip_bfloat16*)ws;
    __hip_bfloat16* Rc   = (__hip_bfloat16*)(ws + 33554432);
    __hip_bfloat16* sA   = (__hip_bfloat16*)(ws + 33554432);
    __hip_bfloat16* Bm   = (__hip_bfloat16*)(ws + 34734080);
    __hip_bfloat16* Ubuf = (__hip_bfloat16*)(ws + 67108864);
    __hip_bfloat16* Vbuf = (__hip_bfloat16*)(ws + 67895296);
    __hip_bfloat16* Aw1  = (__hip_bfloat16*)(ws + 67108864);
    __hip_bfloat16* Aw2  = (__hip_bfloat16*)(ws + 67698688);
    __hip_bfloat16* Aw5  = (__hip_bfloat16*)(ws + 68681728);
    __hip_bfloat16* Aw4  = (__hip_bfloat16*)(ws + 69861376);
    unsigned*       cmaxU = (unsigned*)(ws + 69992448);
    unsigned*       rmaxU = (unsigned*)(ws + 70254592);
    float*          zbuf  = (float*)(ws + 70516736);

    // fused prep: xprep (0..511) + weight prep/zero/sA (512..1664)
    k_prep<<<dim3(1665), 512, 0, stream>>>(
        x, Xc, p1_w, p2_w, c2_w, c1_w, p_w, Aw1, Aw2, Aw5, Aw4, sA,
        (f32x4*)(ws + 69992448));

    // fused K1+K2: blockIdx.y = branch (0: colmax/Aw1, 1: rowmax/Aw2)
    k_conv3<1><<<dim3(64, 2, 4), 256, 0, stream>>>(
        Xc, Aw1, Aw2, zbuf,
        p1_g, p1_b, p1_m, p1_v, p2_g, p2_b, p2_m, p2_v,
        nullptr, cmaxU, rmaxU, CMID);

    // im2col of the pool maxes, then U/V via MFMA GEMM (replaces k_uv)
    k_b2<<<dim3(8, 2, 4), 256, 0, stream>>>(
        (const float*)cmaxU, (const float*)rmaxU, Bm);
    k_uv_mfma<<<dim3(3, 4, 2), 256, 0, stream>>>(sA, Bm, Ubuf, Vbuf);

    k_merge_mfma<<<dim3(128, 4), 256, 0, stream>>>(
        Xc, Aw4, Ubuf, Vbuf, p_g, p_b, p_m, p_v,
        c1_g, c1_b, c1_m, c1_v, Rc);

    // K5: blockIdx.y = co-tile
    k_conv3<0><<<dim3(64, 2, 4), 256, 0, stream>>>(
        Rc, Aw5, nullptr, zbuf,
        c2_g, c2_b, c2_m, c2_v, nullptr, nullptr, nullptr, nullptr,
        out, nullptr, nullptr, CDIM);
}

// Round 11
// 337.072 us; speedup vs baseline: 1.1306x; 1.0354x over previous
//
#include <hip/hip_runtime.h>
#include <hip/hip_bf16.h>
#include <math.h>

// pool_cross on MI355X — round 18.
// r17 established: harness dur_us is stable (+-1us); rocprof per-dispatch
// durations swing +-20% with clock state (conv3 76 vs 91us on identical
// source+total). r16's +31us was the fused-im2col uv (not conv3). Standing
// best 349us. conv3 closed (5 failed structural attempts). This round:
//   (1) k_uv_mfma co-split: 24 -> 48 blocks (grid 6,4,2), each 128co x
//       128p (wave=32co, acc[2][8], 256 LDS rows = 32KB). The kernel is
//       serial-depth-bound at 9% machine occupancy; halving per-block
//       work should ~halve its ~18us.
//   (2) k_prep x-loads via __builtin_nontemporal_load: x is read-once
//       (67MB); don't evict L2/L3 lines that Xc/weights want resident.
// All else byte-identical to the verified 349us build.
//
// pool algebra (verified): bottom(top(a)) = colmax bcast, right(left(a)) =
// rowmax bcast; merge conv input is rank-1 -> 1-D k_uv decomposition.
// Pool maxes via atomicMax on fp32 bits (valid: values >= 0 post-relu).

constexpr int NB   = 4;
constexpr int CDIM = 256;
constexpr int CMID = 128;
constexpr int HS   = 128;
constexpr int WS   = 128;
constexpr float EPS = 1e-5f;

typedef __bf16 bf16x8 __attribute__((ext_vector_type(8)));
typedef float  f32x4  __attribute__((ext_vector_type(4)));

#define AS1 __attribute__((address_space(1)))
#define AS3 __attribute__((address_space(3)))

__device__ __forceinline__ void load16_lds(const void* gsrc, void* ldst) {
    __builtin_amdgcn_global_load_lds((const AS1 unsigned int*)gsrc,
                                     (AS3 unsigned int*)ldst, 16, 0, 0);
}

// ---------------------------------------------------------------------------
// Fused prep: blocks 0..511 = xprep (x[b][ci][y][x] fp32 -> Xc[b][y][x][ci]
// bf16, LDS transpose, XOR-swizzled); blocks 512..1664 = weight prep +
// zero-fill + sA (two 256-thread units per block).
__global__ __launch_bounds__(512) void k_prep(
    const float* __restrict__ xin, __hip_bfloat16* __restrict__ Xc,
    const float* __restrict__ p1w, const float* __restrict__ p2w,
    const float* __restrict__ c2w, const float* __restrict__ c1w,
    const float* __restrict__ pw,
    __hip_bfloat16* __restrict__ Aw1, __hip_bfloat16* __restrict__ Aw2,
    __hip_bfloat16* __restrict__ Aw5, __hip_bfloat16* __restrict__ Aw4,
    __hip_bfloat16* __restrict__ sA,
    f32x4* __restrict__ zdst)
{
    __shared__ __hip_bfloat16 lds[128 * 264];   // [x][ci'], ci XOR-swizzled
    const int bid = blockIdx.x;
    const int t   = threadIdx.x;

    if (bid < 512) {
        const int y = bid >> 2;
        const int b = bid & 3;
        const float* xrow = xin + ((size_t)b * CDIM * HS + y) * WS;
#pragma unroll
        for (int k = 0; k < 8; ++k) {
            int idx = t + k * 512;            // 0..4095
            int cip = idx >> 5;               // ci pair 0..127
            int x4  = idx & 31;
            int ci  = cip * 2;
            f32x4 va = __builtin_nontemporal_load(
                (const f32x4*)(xrow + (size_t)ci       * HS * WS + x4 * 4));
            f32x4 vb = __builtin_nontemporal_load(
                (const f32x4*)(xrow + (size_t)(ci + 1) * HS * WS + x4 * 4));
            const int cis = ci ^ ((x4 & 7) << 3);   // swizzle: (x>>2)&7 on bits 3..5
#pragma unroll
            for (int j = 0; j < 4; ++j) {
                __hip_bfloat162 pv;
                pv.x = __float2bfloat16(va[j]);
                pv.y = __float2bfloat16(vb[j]);
                *(__hip_bfloat162*)(lds + (size_t)(x4 * 4 + j) * 264 + cis) = pv;
            }
        }
        __syncthreads();
#pragma unroll
        for (int k = 0; k < 8; ++k) {
            int i = t + k * 512;              // 0..4095 chunks of 16B
            int x = i >> 5, c8 = i & 31;
            int cb = c8 ^ ((x >> 2) & 7);     // inverse of the write swizzle
            bf16x8 vv = *(const bf16x8*)(lds + (size_t)x * 264 + cb * 8);
            *(bf16x8*)(Xc + ((size_t)(b * 128 + y) * 128 + x) * 256 + c8 * 8) = vv;
        }
        return;
    }

    // unit u, tl = thread 0..255
    const int u  = (bid - 512) * 2 + (t >> 8);
    const int tl = t & 255;
    if (u < 512) {
        const float* W; __hip_bfloat16* A; int co;
        if (u < 128)      { W = p1w; A = Aw1; co = u; }
        else if (u < 256) { W = p2w; A = Aw2; co = u - 128; }
        else              { W = c2w; A = Aw5; co = u - 256; }
#pragma unroll
        for (int tap = 0; tap < 9; ++tap)
            A[(size_t)co * 2304 + tap * 256 + tl] =
                __float2bfloat16(W[((size_t)co * CDIM + tl) * 9 + tap]);
    } else if (u < 640) {
        int base = (u - 512) * 512 + tl;
        Aw4[base]       = __float2bfloat16(c1w[base]);
        Aw4[base + 256] = __float2bfloat16(c1w[base + 256]);
    } else if (u < 768) {
        zdst[(size_t)(u - 640) * 256 + tl] = (f32x4){0.f, 0.f, 0.f, 0.f};
    } else if (u == 768) {
        if (tl < 16) zdst[32768 + tl] = (f32x4){0.f, 0.f, 0.f, 0.f};
    } else if (u >= 770 && u < 2306) {
        // sA: combined merge-conv weights for the U/V GEMM.
        const int su  = u - 770;           // 0..1535
        const int m   = su >= 768;
        const int rem = su - m * 768;
        const int v   = rem >> 8;          // 0..2
        const int co  = rem & 255;
        const float* w9p = pw + ((size_t)co * CMID) * 9;
#pragma unroll
        for (int rep = 0; rep < 2; ++rep) {
            int kk = tl + rep * 256;
            if (kk < 384) {
                int ci = kk / 3, k = kk - 3 * (kk / 3);
                const float* w9 = w9p + (size_t)ci * 9;
                int i0 = m ? k * 3 + 0 : k;
                int i1 = m ? k * 3 + 1 : 3 + k;
                int i2 = m ? k * 3 + 2 : 6 + k;
                float s = w9[i1];                 // j=1 always
                if (v >= 1) s += w9[i0];          // j=0 for v in {1,2}
                if (v <= 1) s += w9[i2];          // j=2 for v in {0,1}
                sA[((size_t)(m * 3 + v) * 256 + co) * 384 + kk] = __float2bfloat16(s);
            }
        }
    }
}

// ---------------------------------------------------------------------------
// Conv3x3 implicit GEMM v2 (r7 proven, verbatim): 2 y-rows x 128co x 128x
// per block, 32-ci chunks, 64B LDS rows with slot = c ^ ((row>>1)&3)
// swizzle (8-row bank-group period).
// MODE 0: plain fp32 NCHW store (K5, nontemporal). MODE 1: fused branches
// (K1+K2): blockIdx.y==0 -> colmax atomics, ==1 -> rowmax (LDS pre-reduce).
template<int MODE>
__global__ __launch_bounds__(256, 2) void k_conv3(
    const __hip_bfloat16* __restrict__ Xc,
    const __hip_bfloat16* __restrict__ AwA, const __hip_bfloat16* __restrict__ AwB,
    const float* __restrict__ zbuf,
    const float* __restrict__ g1, const float* __restrict__ b1,
    const float* __restrict__ m1, const float* __restrict__ v1,
    const float* __restrict__ g2, const float* __restrict__ b2,
    const float* __restrict__ m2, const float* __restrict__ v2,
    float* __restrict__ out0, unsigned* __restrict__ cmax,
    unsigned* __restrict__ rmax, int CO)
{
    const int y0     = blockIdx.x * 2;
    const int branch = blockIdx.y;              // MODE1: branch; MODE0: co-tile
    const int b      = blockIdx.z;
    const int co0    = (MODE == 0) ? branch * 128 : 0;

    const __hip_bfloat16* Aw = (MODE == 1 && branch) ? AwB : AwA;
    const float* gg  = (MODE == 1 && branch) ? g2 : g1;
    const float* bbp = (MODE == 1 && branch) ? b2 : b1;
    const float* mmp = (MODE == 1 && branch) ? m2 : m1;
    const float* vvp = (MODE == 1 && branch) ? v2 : v1;

    __shared__ __hip_bfloat16 smem[644 * 32];   // 644 rows x 64 B = 41,216 B
    __shared__ float s_sc[128], s_sh[128];
    __shared__ unsigned s_red[2][128];
    char* smb = (char*)smem;

    const int t    = threadIdx.x;
    const int lane = t & 63;
    const int w    = t >> 6;
    const int ml   = lane & 15;
    const int q    = lane >> 4;
    const int mbase = (w >> 1) * 64;
    const int nbase = (w & 1) * 64;

    if (t < 128) {
        int co = co0 + t;
        float iv = rsqrtf(vvp[co] + EPS);
        float sc = gg[co] * iv;
        s_sc[t] = sc;
        s_sh[t] = bbp[co] - mmp[co] * sc;
        if (MODE == 1) { s_red[0][t] = 0u; s_red[1][t] = 0u; }
    }

    f32x4 acc[2][4][4];
#pragma unroll
    for (int yy = 0; yy < 2; ++yy)
#pragma unroll
        for (int mt = 0; mt < 4; ++mt)
#pragma unroll
            for (int nt = 0; nt < 4; ++nt)
                acc[yy][mt][nt] = (f32x4){0.f, 0.f, 0.f, 0.f};

    const __hip_bfloat16* bbase = Xc + (size_t)(b * 128) * 128 * 256;

#pragma unroll 1
    for (int ky = 0; ky < 3; ++ky) {
        const int yd0 = y0 + ky - 1;
        const __hip_bfloat16* arow = Aw + (size_t)co0 * 2304 + (3 * ky) * 256;
#pragma unroll 1
        for (int cih = 0; cih < 8; ++cih) {
            const int cb = cih * 32;
            // stage 2576 x 16B; slot sl holds logical chunk sl^((row>>1)&3)
#pragma unroll
            for (int p = 0; p < 11; ++p) {
                int i = t + p * 256;
                if (i < 2576) {
                    int row = i >> 2, sl = i & 3;
                    int c = sl ^ ((row >> 1) & 3);
                    const __hip_bfloat16* src;
                    if (row < 384) {
                        int j = row >> 7, col = row & 127;
                        src = arow + (size_t)col * 2304 + j * 256 + cb + c * 8;
                    } else {
                        int rbi = row - 384;
                        int yy  = rbi >= 130;
                        int xi  = rbi - 130 * yy;
                        int gy  = yd0 + yy, gx = xi - 1;
                        src = ((unsigned)gy < 128u && (unsigned)gx < 128u)
                            ? bbase + ((size_t)(gy * 128 + gx)) * 256 + cb + c * 8
                            : (const __hip_bfloat16*)((const char*)zbuf + c * 16);
                    }
                    load16_lds(src, smb + (size_t)i * 16);
                }
            }
            __syncthreads();
            // 3 kx, A-frag shared across 2 y rows
#pragma unroll
            for (int j = 0; j < 3; ++j) {
                bf16x8 af[4];
#pragma unroll
                for (int mt = 0; mt < 4; ++mt) {
                    const int ra = j * 128 + mbase + mt * 16 + ml;
                    const int sa = q ^ ((ra >> 1) & 3);
                    af[mt] = *(const bf16x8*)(smb + (size_t)ra * 64 + sa * 16);
                }
#pragma unroll
                for (int yy = 0; yy < 2; ++yy) {
                    bf16x8 bfv[4];
#pragma unroll
                    for (int nt = 0; nt < 4; ++nt) {
                        const int rb = 384 + yy * 130 + nbase + nt * 16 + ml + j;
                        const int sb = q ^ ((rb >> 1) & 3);
                        bfv[nt] = *(const bf16x8*)(smb + (size_t)rb * 64 + sb * 16);
                    }
#pragma unroll
                    for (int mt = 0; mt < 4; ++mt)
#pragma unroll
                        for (int nt = 0; nt < 4; ++nt)
                            acc[yy][mt][nt] = __builtin_amdgcn_mfma_f32_16x16x32_bf16(
                                af[mt], bfv[nt], acc[yy][mt][nt], 0, 0, 0);
                }
            }
            __syncthreads();
        }
    }

    // epilogue. C/D: col(x)=ml, row(co)=q*4+r.
#pragma unroll
    for (int mt = 0; mt < 4; ++mt) {
#pragma unroll
        for (int r = 0; r < 4; ++r) {
            const int col = mbase + mt * 16 + q * 4 + r;
            const float sc = s_sc[col], sh = s_sh[col];
            const int co = co0 + col;
            unsigned rmx0 = 0u, rmx1 = 0u;
#pragma unroll
            for (int nt = 0; nt < 4; ++nt) {
                float va = fmaxf(acc[0][mt][nt][r] * sc + sh, 0.f);
                float vb = fmaxf(acc[1][mt][nt][r] * sc + sh, 0.f);
                const int x = nbase + nt * 16 + ml;
                if (MODE == 0) {
                    __builtin_nontemporal_store(va,
                        out0 + (((size_t)b * CO + co) * HS + y0)     * WS + x);
                    __builtin_nontemporal_store(vb,
                        out0 + (((size_t)b * CO + co) * HS + y0 + 1) * WS + x);
                } else if (branch == 0) {
                    atomicMax(cmax + ((size_t)(b * 128 + co)) * 128 + x,
                              __float_as_uint(fmaxf(va, vb)));
                } else {
                    rmx0 = max(rmx0, __float_as_uint(va));
                    rmx1 = max(rmx1, __float_as_uint(vb));
                }
            }
            if (MODE == 1 && branch == 1) {
                atomicMax(&s_red[0][col], rmx0);
                atomicMax(&s_red[1][col], rmx1);
            }
        }
    }
    if (MODE == 1 && branch == 1) {
        __syncthreads();
        if (t < 128) {
            atomicMax(rmax + ((size_t)(b * 128 + t)) * 128 + y0,     s_red[0][t]);
            atomicMax(rmax + ((size_t)(b * 128 + t)) * 128 + y0 + 1, s_red[1][t]);
        }
    }
}

// ---------------------------------------------------------------------------
// K3a: im2col of cmax/rmax -> Bm[m][b][p][ci*3+k] bf16 (0-padded taps).
__global__ __launch_bounds__(256) void k_b2(
    const float* __restrict__ cm, const float* __restrict__ rm,
    __hip_bfloat16* __restrict__ Bm)
{
    const int p0 = blockIdx.x * 16;
    const int m  = blockIdx.y;
    const int b  = blockIdx.z;
    const int tl = threadIdx.x;
    const float* basep = (m == 0) ? cm : rm;
#pragma unroll
    for (int rep = 0; rep < 2; ++rep) {
        int kk = tl + rep * 256;
        if (kk < 384) {
            int ci = kk / 3, k = kk - 3 * (kk / 3);
            const float* src = basep + ((size_t)b * 128 + ci) * 128;
            __hip_bfloat16* dst = Bm + ((size_t)(m * 4 + b) * 128) * 384 + kk;
#pragma unroll
            for (int pp = 0; pp < 16; ++pp) {
                int p = p0 + pp;
                int pos = p + k - 1;
                float vv = ((unsigned)pos < 128u) ? src[pos] : 0.f;
                dst[(size_t)p * 384] = __float2bfloat16(vv);
            }
        }
    }
}

// ---------------------------------------------------------------------------
// K3b: U/V as MFMA GEMM, co-split for parallelism (48 blocks, was 24).
// Per block (vc = v*2+coh, b, m): Out[128co][128p] over K=384, 6 K-steps,
// merge_mfma staging/swizzle/frag structure (proven). 4 waves x 32co.
// U written co-major [v][b][co][p]; V written p-major [v][b][p][co].
__global__ __launch_bounds__(256, 2) void k_uv_mfma(
    const __hip_bfloat16* __restrict__ sA, const __hip_bfloat16* __restrict__ Bm,
    __hip_bfloat16* __restrict__ U, __hip_bfloat16* __restrict__ V)
{
    const int vc = blockIdx.x;  // v*2 + co-half
    const int v  = vc >> 1;
    const int coh = vc & 1;
    const int b = blockIdx.y;   // batch
    const int m = blockIdx.z;   // mode: 0 -> U, 1 -> V
    const __hip_bfloat16* A  = sA + ((size_t)((m * 3 + v) * 256) + coh * 128) * 384;
    const __hip_bfloat16* Bp = Bm + (size_t)((m * 4 + b) * 128) * 384;

    __shared__ __hip_bfloat16 smem[16384];   // 32 KB: 256 rows x 128 B
    char* smb = (char*)smem;
    const int t = threadIdx.x, lane = t & 63, w = t >> 6;
    const int ml = lane & 15, q = lane >> 4;
    const int mbase = w * 32;                // wave's co offset (32 co/wave)

    f32x4 acc[2][8];
#pragma unroll
    for (int mt = 0; mt < 2; ++mt)
#pragma unroll
        for (int nt = 0; nt < 8; ++nt)
            acc[mt][nt] = (f32x4){0.f, 0.f, 0.f, 0.f};

#pragma unroll 1
    for (int ks = 0; ks < 6; ++ks) {
        // stage 256 rows x 128B: A rows 0..127 (co), B rows 128..255 (p)
#pragma unroll
        for (int p = 0; p < 8; ++p) {
            int i   = t + p * 256;           // 0..2047
            int row = i >> 3, sl = i & 7;
            int c   = sl ^ (row & 7);
            const __hip_bfloat16* src = (row < 128)
                ? A  + (size_t)row * 384 + ks * 64 + c * 8
                : Bp + (size_t)(row - 128) * 384 + ks * 64 + c * 8;
            load16_lds(src, smb + (size_t)i * 16);
        }
        __syncthreads();
#pragma unroll
        for (int s = 0; s < 2; ++s) {
            bf16x8 af[2], bfv[8];
#pragma unroll
            for (int mt = 0; mt < 2; ++mt) {
                const int ra = mbase + mt * 16 + ml;
                const int coff = ((s * 4 + q) ^ (ra & 7)) * 16;
                af[mt] = *(const bf16x8*)(smb + (size_t)ra * 128 + coff);
            }
#pragma unroll
            for (int nt = 0; nt < 8; ++nt) {
                const int rb = 128 + nt * 16 + ml;
                const int coff = ((s * 4 + q) ^ (rb & 7)) * 16;
                bfv[nt] = *(const bf16x8*)(smb + (size_t)rb * 128 + coff);
            }
#pragma unroll
            for (int mt = 0; mt < 2; ++mt)
#pragma unroll
                for (int nt = 0; nt < 8; ++nt)
                    acc[mt][nt] = __builtin_amdgcn_mfma_f32_16x16x32_bf16(
                        af[mt], bfv[nt], acc[mt][nt], 0, 0, 0);
        }
        __syncthreads();
    }

    // epilogue: C/D col(p)=ml, row(co)=q*4+r; co_global = coh*128 + local.
    if (m == 0) {
        __hip_bfloat16* dst = U + ((size_t)(v * NB + b) * CDIM) * 128;
#pragma unroll
        for (int mt = 0; mt < 2; ++mt)
#pragma unroll
            for (int nt = 0; nt < 8; ++nt)
#pragma unroll
                for (int r = 0; r < 4; ++r) {
                    const int co = coh * 128 + mbase + mt * 16 + q * 4 + r;
                    const int p  = nt * 16 + ml;
                    dst[(size_t)co * 128 + p] = __float2bfloat16(acc[mt][nt][r]);
                }
    } else {
        // V transposed: [v][b][p][co], 4 consecutive co packed per 8B store
        char* dstb = (char*)V + ((size_t)(v * NB + b) * 128) * 256 * 2;
#pragma unroll
        for (int mt = 0; mt < 2; ++mt)
#pragma unroll
            for (int nt = 0; nt < 8; ++nt) {
                const int p = nt * 16 + ml;
                unsigned long long pk = 0;
#pragma unroll
                for (int r = 0; r < 4; ++r) {
                    __hip_bfloat16 hb = __float2bfloat16(acc[mt][nt][r]);
                    unsigned short bits;
                    __builtin_memcpy(&bits, &hb, 2);
                    pk |= (unsigned long long)bits << (16 * r);
                }
                *(unsigned long long*)(dstb +
                    ((size_t)p * 256 + coh * 128 + mbase + mt * 16 + q * 4) * 2) = pk;
            }
    }
}

// ---------------------------------------------------------------------------
// K4 v2: merge as MFMA GEMM, 256co x 128x per block (one y row), 4 waves,
// wave = 64co x 128x (acc 4x8). 128B LDS rows, slot = c ^ (row&7) swizzle.
// Rc[b][y][x][co] = relu(psc*(U+V)+psh + csc*conv1x1+csh), bf16.
// V is [v][b][p][co] -> init reads coalesced.
__global__ __launch_bounds__(256, 2) void k_merge_mfma(
    const __hip_bfloat16* __restrict__ Xc, const __hip_bfloat16* __restrict__ Aw4,
    const __hip_bfloat16* __restrict__ U, const __hip_bfloat16* __restrict__ V,
    const float* __restrict__ pg, const float* __restrict__ pb,
    const float* __restrict__ pm, const float* __restrict__ pv,
    const float* __restrict__ cg, const float* __restrict__ cb,
    const float* __restrict__ cmn, const float* __restrict__ cv,
    __hip_bfloat16* __restrict__ Rc)
{
    const int y = blockIdx.x;
    const int b = blockIdx.y;
    __shared__ __hip_bfloat16 smem[32768];   // 64 KB: GEMM staging, then U tiles
    __shared__ float s_psc[256], s_psh[256], s_csc[256], s_csh[256];
    __shared__ float s_v0[256], s_vm[256], s_v1[256];
    char* smb = (char*)smem;
    const int t = threadIdx.x, lane = t & 63, w = t >> 6;
    const int ml = lane & 15, q = lane >> 4;
    const int mbase = w * 64;                // wave's co offset
    const int yc = (y == 0) ? 0 : ((y == HS - 1) ? 2 : 1);

    {   // 256 threads cover 256 co; V reads coalesced
        int co = t;
        float iv = rsqrtf(pv[co] + EPS);
        float psc = pg[co] * iv;
        s_psc[co] = psc;
        s_psh[co] = pb[co] - pm[co] * psc;
        float iv2 = rsqrtf(cv[co] + EPS);
        float csc = cg[co] * iv2;
        s_csc[co] = csc;
        s_csh[co] = cb[co] - cmn[co] * csc;
        const size_t vb2 = ((size_t)b * 128 + y) * 256 + co;
        const size_t cstr2 = (size_t)NB * 128 * 256;
        s_v0[co] = __bfloat162float(V[vb2]);
        s_vm[co] = __bfloat162float(V[cstr2 + vb2]);
        s_v1[co] = __bfloat162float(V[2 * cstr2 + vb2]);
    }

    f32x4 acc[4][8];
#pragma unroll
    for (int mt = 0; mt < 4; ++mt)
#pragma unroll
        for (int nt = 0; nt < 8; ++nt)
            acc[mt][nt] = (f32x4){0.f, 0.f, 0.f, 0.f};

    const __hip_bfloat16* brow = Xc + (size_t)(b * 128 + y) * 128 * 256;
#pragma unroll 1
    for (int ks = 0; ks < 4; ++ks) {
        // stage 384 rows x 128B: A rows 0..255 (co), B rows 256..383 (x)
#pragma unroll
        for (int p = 0; p < 12; ++p) {
            int i   = t + p * 256;           // 0..3071
            int row = i >> 3, sl = i & 7;
            int c   = sl ^ (row & 7);
            const __hip_bfloat16* src = (row < 256)
                ? Aw4 + (size_t)row * 256 + ks * 64 + c * 8
                : brow + (size_t)(row - 256) * 256 + ks * 64 + c * 8;
            load16_lds(src, smb + (size_t)i * 16);
        }
        __syncthreads();
#pragma unroll
        for (int s = 0; s < 2; ++s) {
            bf16x8 af[4], bfv[8];
#pragma unroll
            for (int mt = 0; mt < 4; ++mt) {
                const int ra = mbase + mt * 16 + ml;
                const int coff = ((s * 4 + q) ^ (ra & 7)) * 16;
                af[mt] = *(const bf16x8*)(smb + (size_t)ra * 128 + coff);
            }
#pragma unroll
            for (int nt = 0; nt < 8; ++nt) {
                const int rb = 256 + nt * 16 + ml;
                const int coff = ((s * 4 + q) ^ (rb & 7)) * 16;
                bfv[nt] = *(const bf16x8*)(smb + (size_t)rb * 128 + coff);
            }
#pragma unroll
            for (int mt = 0; mt < 4; ++mt)
#pragma unroll
                for (int nt = 0; nt < 8; ++nt)
                    acc[mt][nt] = __builtin_amdgcn_mfma_f32_16x16x32_bf16(
                        af[mt], bfv[nt], acc[mt][nt], 0, 0, 0);
        }
        __syncthreads();
    }

    // per-wave U stage: 64co x 128x bf16 = 16 KB at wave offset (contiguous)
    const __hip_bfloat16* Ub = U + ((size_t)(yc * NB + b) * CDIM + mbase) * 128;
#pragma unroll
    for (int k = 0; k < 16; ++k) {
        int i = lane + k * 64;
        load16_lds(Ub + (size_t)i * 8, smb + (size_t)w * 16384 + (size_t)i * 16);
    }
    __syncthreads();
    const __hip_bfloat16* ulds = smem + w * 8192;

#pragma unroll
    for (int mt = 0; mt < 4; ++mt) {
#pragma unroll
        for (int nt = 0; nt < 8; ++nt) {
            const int x = nt * 16 + ml;
            unsigned long long pk = 0;
#pragma unroll
            for (int r = 0; r < 4; ++r) {
                const int cl = mt * 16 + q * 4 + r;       // local co in wave
                const int co = mbase + cl;
                float u  = __bfloat162float(ulds[cl * 128 + x]);
                float vt = (x == 0) ? s_v0[co] : ((x == WS - 1) ? s_v1[co] : s_vm[co]);
                float val = fmaxf((u + vt) * s_psc[co] + s_psh[co]
                                  + acc[mt][nt][r] * s_csc[co] + s_csh[co], 0.f);
                __hip_bfloat16 hb = __float2bfloat16(val);
                unsigned short bits;
                __builtin_memcpy(&bits, &hb, 2);
                pk |= (unsigned long long)bits << (16 * r);
            }
            *(unsigned long long*)((char*)Rc +
                ((size_t)((b * 128 + y) * 128 + x) * 256 + mbase + mt * 16 + q * 4) * 2) = pk;
        }
    }
}

// ---------------------------------------------------------------------------
extern "C" void kernel_launch(void* const* d_in, const int* in_sizes, int n_in,
                              void* d_out, int out_size, void* d_ws, size_t ws_size,
                              hipStream_t stream)
{
    (void)in_sizes; (void)n_in; (void)out_size; (void)ws_size;
    const float* x    = (const float*)d_in[0];
    const float* p1_w = (const float*)d_in[1];
    const float* p1_g = (const float*)d_in[2];
    const float* p1_b = (const float*)d_in[3];
    const float* p1_m = (const float*)d_in[4];
    const float* p1_v = (const float*)d_in[5];
    const float* p2_w = (const float*)d_in[6];
    const float* p2_g = (const float*)d_in[7];
    const float* p2_b = (const float*)d_in[8];
    const float* p2_m = (const float*)d_in[9];
    const float* p2_v = (const float*)d_in[10];
    const float* p_w  = (const float*)d_in[11];
    const float* p_g  = (const float*)d_in[12];
    const float* p_b  = (const float*)d_in[13];
    const float* p_m  = (const float*)d_in[14];
    const float* p_v  = (const float*)d_in[15];
    const float* c1_w = (const float*)d_in[16];
    const float* c1_g = (const float*)d_in[17];
    const float* c1_b = (const float*)d_in[18];
    const float* c1_m = (const float*)d_in[19];
    const float* c1_v = (const float*)d_in[20];
    const float* c2_w = (const float*)d_in[21];
    const float* c2_g = (const float*)d_in[22];
    const float* c2_b = (const float*)d_in[23];
    const float* c2_m = (const float*)d_in[24];
    const float* c2_v = (const float*)d_in[25];
    float* out = (float*)d_out;
    char* ws = (char*)d_ws;

    // layout (bytes), total 70,516,992 (<= proven-safe 70,778,880):
    //   Xc @0 (33,554,432) | Rc @33,554,432 (33,554,432)
    //     sA @33,554,432 (1,179,648) and Bm @34,734,080 (786,432) alias the
    //     head of Rc: both dead before k_merge_mfma writes Rc (stream order).
    //   U @67,108,864 / V @67,895,296 (alias Aw1 @67,108,864, Aw2 @67,698,688)
    //   Aw5 @68,681,728 | Aw4 @69,861,376
    //   zero region @69,992,448 (524,544): cmaxU | rmaxU @70,254,592 | zbuf @70,516,736
    __hip_bfloat16* Xc   = (__hip_bfloat16*)ws;
    __hip_bfloat16* Rc   = (__hip_bfloat16*)(ws + 33554432);
    __hip_bfloat16* sA   = (__hip_bfloat16*)(ws + 33554432);
    __hip_bfloat16* Bm   = (__hip_bfloat16*)(ws + 34734080);
    __hip_bfloat16* Ubuf = (__hip_bfloat16*)(ws + 67108864);
    __hip_bfloat16* Vbuf = (__hip_bfloat16*)(ws + 67895296);
    __hip_bfloat16* Aw1  = (__hip_bfloat16*)(ws + 67108864);
    __hip_bfloat16* Aw2  = (__hip_bfloat16*)(ws + 67698688);
    __hip_bfloat16* Aw5  = (__hip_bfloat16*)(ws + 68681728);
    __hip_bfloat16* Aw4  = (__hip_bfloat16*)(ws + 69861376);
    unsigned*       cmaxU = (unsigned*)(ws + 69992448);
    unsigned*       rmaxU = (unsigned*)(ws + 70254592);
    float*          zbuf  = (float*)(ws + 70516736);

    // fused prep: xprep (0..511) + weight prep/zero/sA (512..1664)
    k_prep<<<dim3(1665), 512, 0, stream>>>(
        x, Xc, p1_w, p2_w, c2_w, c1_w, p_w, Aw1, Aw2, Aw5, Aw4, sA,
        (f32x4*)(ws + 69992448));

    // fused K1+K2: blockIdx.y = branch (0: colmax/Aw1, 1: rowmax/Aw2)
    k_conv3<1><<<dim3(64, 2, 4), 256, 0, stream>>>(
        Xc, Aw1, Aw2, zbuf,
        p1_g, p1_b, p1_m, p1_v, p2_g, p2_b, p2_m, p2_v,
        nullptr, cmaxU, rmaxU, CMID);

    // im2col of the pool maxes, then U/V via MFMA GEMM (co-split, 48 blocks)
    k_b2<<<dim3(8, 2, 4), 256, 0, stream>>>(
        (const float*)cmaxU, (const float*)rmaxU, Bm);
    k_uv_mfma<<<dim3(6, 4, 2), 256, 0, stream>>>(sA, Bm, Ubuf, Vbuf);

    k_merge_mfma<<<dim3(128, 4), 256, 0, stream>>>(
        Xc, Aw4, Ubuf, Vbuf, p_g, p_b, p_m, p_v,
        c1_g, c1_b, c1_m, c1_v, Rc);

    // K5: blockIdx.y = co-tile
    k_conv3<0><<<dim3(64, 2, 4), 256, 0, stream>>>(
        Rc, Aw5, nullptr, zbuf,
        c2_g, c2_b, c2_m, c2_v, nullptr, nullptr, nullptr, nullptr,
        out, nullptr, nullptr, CDIM);
}